// Round 4
// baseline (17388.409 us; speedup 1.0000x reference)
//
#include <hip/hip_runtime.h>

#define T_ 1024
#define B_ 32
#define D_ 512
#define FF_ 2048
#define TB_ 32768   // T_*B_
#define TCH_ 256    // T chunk
#define RCH_ 8192   // TCH_*B_ rows per chunk

typedef short bf16x8 __attribute__((ext_vector_type(8)));
typedef float f32x4 __attribute__((ext_vector_type(4)));

static __device__ __forceinline__ unsigned int pack2bf(float a, float b){
  union { __bf16 h[2]; unsigned int u; } z;
  z.h[0] = (__bf16)a; z.h[1] = (__bf16)b; return z.u;
}
static __device__ __forceinline__ float bflo(unsigned int u){ return __uint_as_float(u<<16); }
static __device__ __forceinline__ float bfhi(unsigned int u){ return __uint_as_float(u & 0xffff0000u); }
static __device__ __forceinline__ float sigm(float x){ return 1.f/(1.f+__expf(-x)); }
static __device__ __forceinline__ float tanh_(float x){ return 1.f - 2.f/(1.f+__expf(2.f*x)); }

// first[] may be uint8 (numpy bool) or int32; detected at runtime.
static __device__ __forceinline__ bool firstval(const void* p, int mode, int idx){
  return mode ? (((const int*)p)[idx] != 0) : (((const unsigned char*)p)[idx] != 0);
}

// ---------------------------------------------------------------- detect bool dtype
__global__ void detect_first_kernel(const unsigned char* __restrict__ p, unsigned int* __restrict__ mode){
  __shared__ int found;
  if (threadIdx.x == 0) found = 0;
  __syncthreads();
  int f = 0;
  for (int i = threadIdx.x; i < TB_; i += 256) if ((i & 3) != 0 && p[i] != 0) f = 1;
  if (f) atomicAdd(&found, 1);
  __syncthreads();
  if (threadIdx.x == 0) *mode = (found == 0) ? 1u : 0u;   // 1 => int32, 0 => uint8
}

// ---------------------------------------------------------------- weight conversion
__global__ void convert_w_kernel(const float* __restrict__ Wih, const float* __restrict__ Whh,
                                 const float* __restrict__ m0w, const float* __restrict__ m1w,
                                 const float* __restrict__ aw0, const float* __restrict__ aw1,
                                 __bf16* __restrict__ Wihb, __bf16* __restrict__ Whhb,
                                 __bf16* __restrict__ m0b,  __bf16* __restrict__ m1b,
                                 __bf16* __restrict__ awT0, __bf16* __restrict__ awT1){
  int bid = blockIdx.x;
  if (bid < 4096) {
    int ai = bid >> 10;
    size_t off = (size_t)(bid & 1023) * 1024 + threadIdx.x * 4;
    const float* src = (ai==0)?Wih:(ai==1)?Whh:(ai==2)?m0w:m1w;
    __bf16* dst = (ai==0)?Wihb:(ai==1)?Whhb:(ai==2)?m0b:m1b;
    float4 v = *(const float4*)(src + off);
    union { __bf16 h[4]; uint2 u; } z;
    z.h[0]=(__bf16)v.x; z.h[1]=(__bf16)v.y; z.h[2]=(__bf16)v.z; z.h[3]=(__bf16)v.w;
    *(uint2*)(void*)(dst + off) = z.u;
  } else {
    int e = (bid - 4096) * 256 + threadIdx.x;      // 0..65535
    if (e < 32768) { int k = e >> 6, j = e & 63;  awT0[e] = (__bf16)aw0[j*512 + k]; }
    else { int e2 = e - 32768; int j = e2 >> 9, d = e2 & 511; awT1[e2] = (__bf16)aw1[d*64 + j]; }
  }
}

// ---------------------------------------------------------------- layernorm -> bf16 (chunk of 8192 rows)
__global__ __launch_bounds__(256) void ln_kernel(const float* __restrict__ x,
                                                 const float* __restrict__ g, const float* __restrict__ b,
                                                 __bf16* __restrict__ xn){
  const int w = threadIdx.x >> 6, l = threadIdx.x & 63;
  const int row = blockIdx.x * 4 + w;
  const float* xr = x + (size_t)row * D_;
  const int e0 = l * 4, e1 = 256 + l * 4;
  float4 v0 = *(const float4*)(xr + e0);
  float4 v1 = *(const float4*)(xr + e1);
  float s  = v0.x+v0.y+v0.z+v0.w + v1.x+v1.y+v1.z+v1.w;
  float s2 = v0.x*v0.x+v0.y*v0.y+v0.z*v0.z+v0.w*v0.w + v1.x*v1.x+v1.y*v1.y+v1.z*v1.z+v1.w*v1.w;
  #pragma unroll
  for (int off = 1; off < 64; off <<= 1) { s += __shfl_xor(s, off); s2 += __shfl_xor(s2, off); }
  float mu = s * (1.f/512.f);
  float var = s2 * (1.f/512.f) - mu*mu;
  float rstd = rsqrtf(var + 1e-5f);
  float4 g0 = *(const float4*)(g + e0), g1 = *(const float4*)(g + e1);
  float4 b0 = *(const float4*)(b + e0), b1 = *(const float4*)(b + e1);
  union { __bf16 h[4]; uint2 u; } o0, o1;
  o0.h[0]=(__bf16)((v0.x-mu)*rstd*g0.x+b0.x); o0.h[1]=(__bf16)((v0.y-mu)*rstd*g0.y+b0.y);
  o0.h[2]=(__bf16)((v0.z-mu)*rstd*g0.z+b0.z); o0.h[3]=(__bf16)((v0.w-mu)*rstd*g0.w+b0.w);
  o1.h[0]=(__bf16)((v1.x-mu)*rstd*g1.x+b1.x); o1.h[1]=(__bf16)((v1.y-mu)*rstd*g1.y+b1.y);
  o1.h[2]=(__bf16)((v1.z-mu)*rstd*g1.z+b1.z); o1.h[3]=(__bf16)((v1.w-mu)*rstd*g1.w+b1.w);
  *(uint2*)(void*)(xn + (size_t)row * D_ + e0) = o0.u;
  *(uint2*)(void*)(xn + (size_t)row * D_ + e1) = o1.u;
}

// ---------------------------------------------------------------- bf16 "BT" GEMM  C[M,N] = A[M,K] @ W[N,K]^T + bias
template<int RELU, int BF16OUT, int TWOBIAS>
__global__ __launch_bounds__(256) void gemm_bt(const __bf16* __restrict__ A, const __bf16* __restrict__ W,
                                               const float* __restrict__ bias0, const float* __restrict__ bias1,
                                               float* __restrict__ Cf, __bf16* __restrict__ Cb,
                                               int M, int N, int K){
  __shared__ __bf16 As[128*64];
  __shared__ __bf16 Bs[128*64];
  const int tid = threadIdx.x, w = tid >> 6, l = tid & 63;
  const int bm = blockIdx.x, bn = blockIdx.y;
  const int wm = (w >> 1) * 64, wn = (w & 1) * 64;
  const int nk = K >> 6;

  uint4 ra[4], rb[4];
  #pragma unroll
  for (int i = 0; i < 4; ++i) {
    int s = tid + (i << 8); int row = s >> 3; int ks = s & 7;
    ra[i] = *(const uint4*)(void*)(A + (size_t)(bm*128 + row) * K + ks*8);
    rb[i] = *(const uint4*)(void*)(W + (size_t)(bn*128 + row) * K + ks*8);
  }
  f32x4 acc[4][4];
  #pragma unroll
  for (int mt = 0; mt < 4; ++mt)
    #pragma unroll
    for (int nt = 0; nt < 4; ++nt) acc[mt][nt] = (f32x4){0.f,0.f,0.f,0.f};

  for (int kt = 0; kt < nk; ++kt) {
    __syncthreads();
    #pragma unroll
    for (int i = 0; i < 4; ++i) {
      int s = tid + (i << 8); int row = s >> 3; int ks = s & 7;
      int wi = row * 64 + ((ks * 8) ^ ((row & 7) << 3));   // XOR swizzle (elements)
      *(uint4*)(void*)(As + wi) = ra[i];
      *(uint4*)(void*)(Bs + wi) = rb[i];
    }
    __syncthreads();
    if (kt + 1 < nk) {
      #pragma unroll
      for (int i = 0; i < 4; ++i) {
        int s = tid + (i << 8); int row = s >> 3; int ks = s & 7;
        ra[i] = *(const uint4*)(void*)(A + (size_t)(bm*128 + row) * K + (kt+1)*64 + ks*8);
        rb[i] = *(const uint4*)(void*)(W + (size_t)(bn*128 + row) * K + (kt+1)*64 + ks*8);
      }
    }
    #pragma unroll
    for (int kk = 0; kk < 2; ++kk) {
      bf16x8 af[4], bfv[4];
      const int ke = kk * 32 + ((l >> 4) << 3);
      #pragma unroll
      for (int mt = 0; mt < 4; ++mt) {
        int row = wm + mt*16 + (l & 15);
        af[mt] = *(const bf16x8*)(void*)(As + row*64 + (ke ^ ((row & 7) << 3)));
      }
      #pragma unroll
      for (int nt = 0; nt < 4; ++nt) {
        int row = wn + nt*16 + (l & 15);
        bfv[nt] = *(const bf16x8*)(void*)(Bs + row*64 + (ke ^ ((row & 7) << 3)));
      }
      #pragma unroll
      for (int mt = 0; mt < 4; ++mt)
        #pragma unroll
        for (int nt = 0; nt < 4; ++nt)
          acc[mt][nt] = __builtin_amdgcn_mfma_f32_16x16x32_bf16(af[mt], bfv[nt], acc[mt][nt], 0, 0, 0);
    }
  }
  // epilogue: D row = (l>>4)*4+j, col = l&15 (m89-verified layout)
  #pragma unroll
  for (int nt = 0; nt < 4; ++nt) {
    int c = bn*128 + wn + nt*16 + (l & 15);
    float bv = bias0[c];
    if (TWOBIAS) bv += bias1[c];
    #pragma unroll
    for (int mt = 0; mt < 4; ++mt) {
      #pragma unroll
      for (int j = 0; j < 4; ++j) {
        int r = bm*128 + wm + mt*16 + ((l >> 4) << 2) + j;
        float v = acc[mt][nt][j] + bv;
        if (RELU) v = fmaxf(v, 0.f);
        if (BF16OUT) Cb[(size_t)r * N + c] = (__bf16)v;
        else         Cf[(size_t)r * N + c] = v;
      }
    }
  }
}

// ---------------------------------------------------------------- LSTM scan chunk
// 16 persistent WGs; per-WG tags; incremental slice consumption direct into MFMA regs.
__global__ __launch_bounds__(512) void lstm_scan(
    const __bf16* __restrict__ Whh,      // [2048][512] bf16
    const __bf16* __restrict__ preC,     // [RCH_][2048] bf16 (chunk-local rows)
    const float*  __restrict__ x,        // residual (global rows)
    const void*   __restrict__ firstp,
    const float*  __restrict__ h0,
    const float*  __restrict__ c0,
    float*        __restrict__ cstate,   // [B_*D_] f32, carries c across chunks (pre-multiplied by keep)
    __bf16*       __restrict__ ymidbC,   // [RCH_][512] bf16 (chunk-local rows)
    __bf16*       __restrict__ H2,       // [2][16][1024] bf16 slices
    unsigned int* __restrict__ tags,     // [16], global-t valued
    const unsigned int* __restrict__ modep,
    float* __restrict__ hout, float* __restrict__ cout,
    int tBase){
  const int s = blockIdx.x, tid = threadIdx.x, w = tid >> 6, l = tid & 63;
  const int d0 = s * 32;
  __shared__ float gl[32 * 128];       // gate exchange [b_row][gate_row_local]
  const int mode = (int)*modep;

  // Whh B-fragments resident in VGPRs: wave w owns gate rows rl = w*16 + (l&15)
  // wf[src] covers K-dims src*32..src*32+31 (i.e. h-slice src).
  bf16x8 wf[16];
  {
    int rl = w*16 + (l & 15);
    int gr = (rl >> 5) * 512 + d0 + (rl & 31);     // PyTorch gate order i,f,g,o
    const __bf16* base = Whh + (size_t)gr * 512 + ((l >> 4) << 3);
    #pragma unroll
    for (int kt = 0; kt < 16; ++kt) wf[kt] = *(const bf16x8*)(void*)(base + kt*32);
  }
  const int b = tid >> 4, dl2 = (tid & 15) * 2;    // this thread's (batch,row-pair)
  const int dg = d0 + dl2;
  // reader fragment offsets within a 1024-elem slice (A-frag of 16x16x32)
  const int fo0 = (l & 15) * 32 + ((l >> 4) << 3);
  const int fo1 = fo0 + 512;

  float cr[2];
  if (tBase == 0) {
    float k0 = firstval(firstp, mode, b) ? 0.f : 1.f;
    float2 c2 = *(const float2*)(c0 + (size_t)b*512 + dg);
    cr[0] = c2.x * k0; cr[1] = c2.y * k0;          // keep(first[0]) applied at load (pre-multiplied convention)
    float2 h = *(const float2*)(h0 + (size_t)b*512 + dg);
    // publish own slice of h_0 into buffer 0: offset = s*1024 + 2*tid (contiguous)
    __hip_atomic_store((unsigned int*)(void*)(H2 + (size_t)s*1024 + tid*2), pack2bf(h.x*k0, h.y*k0),
                       __ATOMIC_RELAXED, __HIP_MEMORY_SCOPE_AGENT);
    __syncthreads();
    if (tid == 0) __hip_atomic_store(tags + s, 1u, __ATOMIC_RELEASE, __HIP_MEMORY_SCOPE_AGENT);
  } else {
    float2 c2 = *(const float2*)(cstate + (size_t)b*512 + dg);
    cr[0] = c2.x; cr[1] = c2.y;
  }

  for (int tl = 0; tl < TCH_; ++tl) {
    const int t = tBase + tl;
    const int rowg = t * 32 + b, rowl = tl * 32 + b;
    // prefetch (held in regs; consumed after the sync phases)
    unsigned int pg[4];
    #pragma unroll
    for (int gi = 0; gi < 4; ++gi)
      pg[gi] = *(const unsigned int*)(void*)(preC + (size_t)rowl * 2048 + gi*512 + dg);
    float2 xv = *(const float2*)(x + (size_t)rowg * 512 + dg);
    const bool f_t1 = (t < T_-1) ? firstval(firstp, mode, rowg + 32) : false;

    // incremental: for each source slice, wait for its tag then MFMA immediately
    const __bf16* Hb = H2 + ((size_t)(t & 1) << 14);
    f32x4 acc0 = (f32x4){0.f,0.f,0.f,0.f}, acc1 = (f32x4){0.f,0.f,0.f,0.f};
    for (int i = 0; i < 16; ++i) {
      const int src = (s + 1 + i) & 15;
      while (__hip_atomic_load(tags + src, __ATOMIC_RELAXED, __HIP_MEMORY_SCOPE_AGENT)
             < (unsigned int)(t + 1)) {
        __builtin_amdgcn_s_sleep(1);
      }
      asm volatile("" ::: "memory");   // compiler barrier: slice loads stay after the poll
      const unsigned long long* p0 = (const unsigned long long*)(void*)(Hb + (size_t)src*1024 + fo0);
      const unsigned long long* p1 = (const unsigned long long*)(void*)(Hb + (size_t)src*1024 + fo1);
      unsigned long long a0 = __hip_atomic_load(p0,     __ATOMIC_RELAXED, __HIP_MEMORY_SCOPE_AGENT);
      unsigned long long a1 = __hip_atomic_load(p0 + 1, __ATOMIC_RELAXED, __HIP_MEMORY_SCOPE_AGENT);
      unsigned long long b0 = __hip_atomic_load(p1,     __ATOMIC_RELAXED, __HIP_MEMORY_SCOPE_AGENT);
      unsigned long long b1 = __hip_atomic_load(p1 + 1, __ATOMIC_RELAXED, __HIP_MEMORY_SCOPE_AGENT);
      union { unsigned long long q[2]; bf16x8 v; } A0, A1;
      A0.q[0] = a0; A0.q[1] = a1; A1.q[0] = b0; A1.q[1] = b1;
      acc0 = __builtin_amdgcn_mfma_f32_16x16x32_bf16(A0.v, wf[src], acc0, 0, 0, 0);
      acc1 = __builtin_amdgcn_mfma_f32_16x16x32_bf16(A1.v, wf[src], acc1, 0, 0, 0);
    }
    // gate exchange through LDS
    {
      int col = w*16 + (l & 15);
      #pragma unroll
      for (int j = 0; j < 4; ++j) {
        gl[(((l >> 4) << 2) + j) * 128 + col]        = acc0[j];
        gl[((16 + ((l >> 4) << 2) + j)) * 128 + col] = acc1[j];
      }
    }
    __syncthreads();

    // cell update for (b, dg), (b, dg+1); cr is pre-multiplied by keep(first[t])
    float2 gv[4];
    #pragma unroll
    for (int gi = 0; gi < 4; ++gi) gv[gi] = *(const float2*)(gl + b*128 + gi*32 + dl2);
    const float keep1 = f_t1 ? 0.f : 1.f;
    float hh[2], cc[2];
    #pragma unroll
    for (int p = 0; p < 2; ++p) {
      float gi_ = (p ? gv[0].y : gv[0].x) + (p ? bfhi(pg[0]) : bflo(pg[0]));
      float gf_ = (p ? gv[1].y : gv[1].x) + (p ? bfhi(pg[1]) : bflo(pg[1]));
      float gg_ = (p ? gv[2].y : gv[2].x) + (p ? bfhi(pg[2]) : bflo(pg[2]));
      float go_ = (p ? gv[3].y : gv[3].x) + (p ? bfhi(pg[3]) : bflo(pg[3]));
      float cn = sigm(gf_) * cr[p] + sigm(gi_) * tanh_(gg_);
      float h  = sigm(go_) * tanh_(cn);
      cc[p] = cn; hh[p] = h;
    }
    cr[0] = cc[0] * keep1; cr[1] = cc[1] * keep1;
    float2 yv = { hh[0] + xv.x, hh[1] + xv.y };
    if (t < T_-1) {
      __hip_atomic_store((unsigned int*)(void*)(H2 + (((size_t)((t+1) & 1)) << 14) + (size_t)s*1024 + tid*2),
                         pack2bf(hh[0]*keep1, hh[1]*keep1), __ATOMIC_RELAXED, __HIP_MEMORY_SCOPE_AGENT);
      if (tl == TCH_-1) *(float2*)(cstate + (size_t)b*512 + dg) = make_float2(cr[0], cr[1]);
    } else {
      *(float2*)(hout + (size_t)b*512 + dg) = make_float2(hh[0], hh[1]);
      *(float2*)(cout + (size_t)b*512 + dg) = make_float2(cc[0], cc[1]);
    }
    __syncthreads();   // drains slice stores of all waves before the tag release
    if (tid == 0) __hip_atomic_store(tags + s, (unsigned int)(t + 2), __ATOMIC_RELEASE, __HIP_MEMORY_SCOPE_AGENT);
    // deferred output store (drained under next step's poll phase)
    *(unsigned int*)(void*)(ymidbC + (size_t)rowl * 512 + dg) = pack2bf(yv.x, yv.y);
  }
}

// ---------------------------------------------------------------- fused adapter + final residual (in-place on y2)
__global__ __launch_bounds__(256) void adapter_out_kernel(
    float* __restrict__ y2,              // [RCH_][512] in/out (lives in d_out)
    const __bf16* __restrict__ ymidb,    // [RCH_][512]
    const __bf16* __restrict__ awT0,     // [512][64] = aw0^T
    const __bf16* __restrict__ awT1,     // [64][512] = aw1^T
    const float* __restrict__ ab0, const float* __restrict__ ab1){
  __shared__ float zl[16 * 64];
  const int w = threadIdx.x >> 6, l = threadIdx.x & 63;
  const int r0 = blockIdx.x * 16;
  const float bz = ab0[l];
  #pragma unroll
  for (int rr = 0; rr < 4; ++rr) {
    int rowl = w*4 + rr;
    const float* yr = y2 + (size_t)(r0 + rowl) * 512;
    float acc = bz;
    #pragma unroll 4
    for (int k = 0; k < 512; ++k) acc += yr[k] * (float)awT0[k*64 + l];
    zl[rowl*64 + l] = fmaxf(acc, 0.f);
  }
  __syncthreads();
  #pragma unroll
  for (int rr = 0; rr < 4; ++rr) {
    int rowl = w*4 + rr; int row = r0 + rowl;
    const float* yr = y2  + (size_t)row * 512;
    const __bf16* mr = ymidb + (size_t)row * 512;
    #pragma unroll
    for (int dd = 0; dd < 8; ++dd) {
      int d = dd*64 + l;
      float acc = ab1[d] + yr[d] + (float)mr[d];
      #pragma unroll 4
      for (int j = 0; j < 64; ++j) acc += zl[rowl*64 + j] * (float)awT1[j*512 + d];
      y2[(size_t)row * 512 + d] = acc;
    }
  }
}

// ---------------------------------------------------------------- launch
extern "C" void kernel_launch(void* const* d_in, const int* in_sizes, int n_in,
                              void* d_out, int out_size, void* d_ws, size_t ws_size,
                              hipStream_t stream){
  (void)in_sizes; (void)n_in; (void)out_size; (void)ws_size;
  const float* x    = (const float*)d_in[0];
  const void*  first=               d_in[1];
  const float* h0   = (const float*)d_in[2];
  const float* c0   = (const float*)d_in[3];
  const float* ln_g = (const float*)d_in[4];
  const float* ln_b = (const float*)d_in[5];
  const float* Wih  = (const float*)d_in[6];
  const float* Whh  = (const float*)d_in[7];
  const float* bih  = (const float*)d_in[8];
  const float* bhh  = (const float*)d_in[9];
  const float* m0w  = (const float*)d_in[10];
  const float* m0b  = (const float*)d_in[11];
  const float* m1w  = (const float*)d_in[12];
  const float* m1b  = (const float*)d_in[13];
  const float* aw0  = (const float*)d_in[14];
  const float* ab0  = (const float*)d_in[15];
  const float* aw1  = (const float*)d_in[16];
  const float* ab1  = (const float*)d_in[17];

  // workspace layout — total ~59 MB
  char* ws = (char*)d_ws;
  __bf16* buf0  = (__bf16*)(ws + 0LL);            // 32 MB: preC, later a1C (disjoint lifetimes per chunk)
  __bf16* xnbfC = (__bf16*)(ws + 33554432LL);     // 8 MB
  __bf16* ymidbC= (__bf16*)(ws + 41943040LL);     // 8 MB
  __bf16* wihb  = (__bf16*)(ws + 50331648LL);     // 2 MB
  __bf16* whhb  = (__bf16*)(ws + 52428800LL);     // 2 MB
  __bf16* m0bf  = (__bf16*)(ws + 54525952LL);     // 2 MB
  __bf16* m1bf  = (__bf16*)(ws + 56623104LL);     // 2 MB
  __bf16* awT0  = (__bf16*)(ws + 58720256LL);     // 64 KB
  __bf16* awT1  = (__bf16*)(ws + 58785792LL);     // 64 KB
  __bf16* H2    = (__bf16*)(ws + 58851328LL);     // 64 KB
  float*  cstate= (float*) (ws + 58916864LL);     // 64 KB
  unsigned int* tags  = (unsigned int*)(ws + 58982400LL);
  unsigned int* mode  = tags + 16;
  __bf16* preC = buf0;
  __bf16* a1C  = buf0;

  float* out  = (float*)d_out;
  float* hout = out + (size_t)TB_ * D_;
  float* cout = hout + B_ * D_;

  hipMemsetAsync(tags, 0, 256, stream);
  detect_first_kernel<<<1, 256, 0, stream>>>((const unsigned char*)first, mode);
  convert_w_kernel<<<4352, 256, 0, stream>>>(Wih, Whh, m0w, m1w, aw0, aw1,
                                             wihb, whhb, m0bf, m1bf, awT0, awT1);
  for (int c = 0; c < 4; ++c) {
    const size_t ro = (size_t)c * RCH_;
    ln_kernel<<<RCH_/4, 256, 0, stream>>>(x + ro * D_, ln_g, ln_b, xnbfC);
    gemm_bt<0,1,1><<<dim3(RCH_/128, FF_/128), 256, 0, stream>>>(xnbfC, wihb, bih, bhh,
                                                                nullptr, preC, RCH_, 2048, 512);
    lstm_scan<<<16, 512, 0, stream>>>(whhb, preC, x, first, h0, c0, cstate, ymidbC,
                                      H2, tags, mode, hout, cout, c * TCH_);
    gemm_bt<1,1,0><<<dim3(RCH_/128, FF_/128), 256, 0, stream>>>(ymidbC, m0bf, m0b, nullptr,
                                                                nullptr, a1C, RCH_, FF_, 512);
    gemm_bt<0,0,0><<<dim3(RCH_/128, D_/128), 256, 0, stream>>>(a1C, m1bf, m1b, nullptr,
                                                               out + ro * D_, nullptr, RCH_, D_, FF_);
    adapter_out_kernel<<<RCH_/16, 256, 0, stream>>>(out + ro * D_, ymidbC, awT0, awT1, ab0, ab1);
  }
}

// Round 5
// 10063.370 us; speedup vs baseline: 1.7279x; 1.7279x over previous
//
#include <hip/hip_runtime.h>

#define T_ 1024
#define B_ 32
#define D_ 512
#define FF_ 2048
#define TB_ 32768   // T_*B_
#define TCH_ 256    // T chunk
#define RCH_ 8192   // TCH_*B_ rows per chunk

typedef short bf16x8 __attribute__((ext_vector_type(8)));
typedef float f32x4 __attribute__((ext_vector_type(4)));

static __device__ __forceinline__ unsigned int pack2bf(float a, float b){
  union { __bf16 h[2]; unsigned int u; } z;
  z.h[0] = (__bf16)a; z.h[1] = (__bf16)b; return z.u;
}
static __device__ __forceinline__ float bflo(unsigned int u){ return __uint_as_float(u<<16); }
static __device__ __forceinline__ float bfhi(unsigned int u){ return __uint_as_float(u & 0xffff0000u); }
static __device__ __forceinline__ float sigm(float x){ return 1.f/(1.f+__expf(-x)); }
static __device__ __forceinline__ float tanh_(float x){ return 1.f - 2.f/(1.f+__expf(2.f*x)); }

// first[] may be uint8 (numpy bool) or int32; detected at runtime.
static __device__ __forceinline__ bool firstval(const void* p, int mode, int idx){
  return mode ? (((const int*)p)[idx] != 0) : (((const unsigned char*)p)[idx] != 0);
}

// ---------------------------------------------------------------- detect bool dtype
__global__ void detect_first_kernel(const unsigned char* __restrict__ p, unsigned int* __restrict__ mode){
  __shared__ int found;
  if (threadIdx.x == 0) found = 0;
  __syncthreads();
  int f = 0;
  for (int i = threadIdx.x; i < TB_; i += 256) if ((i & 3) != 0 && p[i] != 0) f = 1;
  if (f) atomicAdd(&found, 1);
  __syncthreads();
  if (threadIdx.x == 0) *mode = (found == 0) ? 1u : 0u;   // 1 => int32, 0 => uint8
}

// ---------------------------------------------------------------- weight conversion
__global__ void convert_w_kernel(const float* __restrict__ Wih, const float* __restrict__ Whh,
                                 const float* __restrict__ m0w, const float* __restrict__ m1w,
                                 const float* __restrict__ aw0, const float* __restrict__ aw1,
                                 __bf16* __restrict__ Wihb, __bf16* __restrict__ Whhb,
                                 __bf16* __restrict__ m0b,  __bf16* __restrict__ m1b,
                                 __bf16* __restrict__ awT0, __bf16* __restrict__ awT1){
  int bid = blockIdx.x;
  if (bid < 4096) {
    int ai = bid >> 10;
    size_t off = (size_t)(bid & 1023) * 1024 + threadIdx.x * 4;
    const float* src = (ai==0)?Wih:(ai==1)?Whh:(ai==2)?m0w:m1w;
    __bf16* dst = (ai==0)?Wihb:(ai==1)?Whhb:(ai==2)?m0b:m1b;
    float4 v = *(const float4*)(src + off);
    union { __bf16 h[4]; uint2 u; } z;
    z.h[0]=(__bf16)v.x; z.h[1]=(__bf16)v.y; z.h[2]=(__bf16)v.z; z.h[3]=(__bf16)v.w;
    *(uint2*)(void*)(dst + off) = z.u;
  } else {
    int e = (bid - 4096) * 256 + threadIdx.x;      // 0..65535
    if (e < 32768) { int k = e >> 6, j = e & 63;  awT0[e] = (__bf16)aw0[j*512 + k]; }
    else { int e2 = e - 32768; int j = e2 >> 9, d = e2 & 511; awT1[e2] = (__bf16)aw1[d*64 + j]; }
  }
}

// ---------------------------------------------------------------- layernorm -> bf16 (chunk of 8192 rows)
__global__ __launch_bounds__(256) void ln_kernel(const float* __restrict__ x,
                                                 const float* __restrict__ g, const float* __restrict__ b,
                                                 __bf16* __restrict__ xn){
  const int w = threadIdx.x >> 6, l = threadIdx.x & 63;
  const int row = blockIdx.x * 4 + w;
  const float* xr = x + (size_t)row * D_;
  const int e0 = l * 4, e1 = 256 + l * 4;
  float4 v0 = *(const float4*)(xr + e0);
  float4 v1 = *(const float4*)(xr + e1);
  float s  = v0.x+v0.y+v0.z+v0.w + v1.x+v1.y+v1.z+v1.w;
  float s2 = v0.x*v0.x+v0.y*v0.y+v0.z*v0.z+v0.w*v0.w + v1.x*v1.x+v1.y*v1.y+v1.z*v1.z+v1.w*v1.w;
  #pragma unroll
  for (int off = 1; off < 64; off <<= 1) { s += __shfl_xor(s, off); s2 += __shfl_xor(s2, off); }
  float mu = s * (1.f/512.f);
  float var = s2 * (1.f/512.f) - mu*mu;
  float rstd = rsqrtf(var + 1e-5f);
  float4 g0 = *(const float4*)(g + e0), g1 = *(const float4*)(g + e1);
  float4 b0 = *(const float4*)(b + e0), b1 = *(const float4*)(b + e1);
  union { __bf16 h[4]; uint2 u; } o0, o1;
  o0.h[0]=(__bf16)((v0.x-mu)*rstd*g0.x+b0.x); o0.h[1]=(__bf16)((v0.y-mu)*rstd*g0.y+b0.y);
  o0.h[2]=(__bf16)((v0.z-mu)*rstd*g0.z+b0.z); o0.h[3]=(__bf16)((v0.w-mu)*rstd*g0.w+b0.w);
  o1.h[0]=(__bf16)((v1.x-mu)*rstd*g1.x+b1.x); o1.h[1]=(__bf16)((v1.y-mu)*rstd*g1.y+b1.y);
  o1.h[2]=(__bf16)((v1.z-mu)*rstd*g1.z+b1.z); o1.h[3]=(__bf16)((v1.w-mu)*rstd*g1.w+b1.w);
  *(uint2*)(void*)(xn + (size_t)row * D_ + e0) = o0.u;
  *(uint2*)(void*)(xn + (size_t)row * D_ + e1) = o1.u;
}

// ---------------------------------------------------------------- bf16 "BT" GEMM  C[M,N] = A[M,K] @ W[N,K]^T + bias
template<int RELU, int BF16OUT, int TWOBIAS>
__global__ __launch_bounds__(256) void gemm_bt(const __bf16* __restrict__ A, const __bf16* __restrict__ W,
                                               const float* __restrict__ bias0, const float* __restrict__ bias1,
                                               float* __restrict__ Cf, __bf16* __restrict__ Cb,
                                               int M, int N, int K){
  __shared__ __bf16 As[128*64];
  __shared__ __bf16 Bs[128*64];
  const int tid = threadIdx.x, w = tid >> 6, l = tid & 63;
  const int bm = blockIdx.x, bn = blockIdx.y;
  const int wm = (w >> 1) * 64, wn = (w & 1) * 64;
  const int nk = K >> 6;

  uint4 ra[4], rb[4];
  #pragma unroll
  for (int i = 0; i < 4; ++i) {
    int s = tid + (i << 8); int row = s >> 3; int ks = s & 7;
    ra[i] = *(const uint4*)(void*)(A + (size_t)(bm*128 + row) * K + ks*8);
    rb[i] = *(const uint4*)(void*)(W + (size_t)(bn*128 + row) * K + ks*8);
  }
  f32x4 acc[4][4];
  #pragma unroll
  for (int mt = 0; mt < 4; ++mt)
    #pragma unroll
    for (int nt = 0; nt < 4; ++nt) acc[mt][nt] = (f32x4){0.f,0.f,0.f,0.f};

  for (int kt = 0; kt < nk; ++kt) {
    __syncthreads();
    #pragma unroll
    for (int i = 0; i < 4; ++i) {
      int s = tid + (i << 8); int row = s >> 3; int ks = s & 7;
      int wi = row * 64 + ((ks * 8) ^ ((row & 7) << 3));   // XOR swizzle (elements)
      *(uint4*)(void*)(As + wi) = ra[i];
      *(uint4*)(void*)(Bs + wi) = rb[i];
    }
    __syncthreads();
    if (kt + 1 < nk) {
      #pragma unroll
      for (int i = 0; i < 4; ++i) {
        int s = tid + (i << 8); int row = s >> 3; int ks = s & 7;
        ra[i] = *(const uint4*)(void*)(A + (size_t)(bm*128 + row) * K + (kt+1)*64 + ks*8);
        rb[i] = *(const uint4*)(void*)(W + (size_t)(bn*128 + row) * K + (kt+1)*64 + ks*8);
      }
    }
    #pragma unroll
    for (int kk = 0; kk < 2; ++kk) {
      bf16x8 af[4], bfv[4];
      const int ke = kk * 32 + ((l >> 4) << 3);
      #pragma unroll
      for (int mt = 0; mt < 4; ++mt) {
        int row = wm + mt*16 + (l & 15);
        af[mt] = *(const bf16x8*)(void*)(As + row*64 + (ke ^ ((row & 7) << 3)));
      }
      #pragma unroll
      for (int nt = 0; nt < 4; ++nt) {
        int row = wn + nt*16 + (l & 15);
        bfv[nt] = *(const bf16x8*)(void*)(Bs + row*64 + (ke ^ ((row & 7) << 3)));
      }
      #pragma unroll
      for (int mt = 0; mt < 4; ++mt)
        #pragma unroll
        for (int nt = 0; nt < 4; ++nt)
          acc[mt][nt] = __builtin_amdgcn_mfma_f32_16x16x32_bf16(af[mt], bfv[nt], acc[mt][nt], 0, 0, 0);
    }
  }
  // epilogue: D row = (l>>4)*4+j, col = l&15 (m89-verified layout)
  #pragma unroll
  for (int nt = 0; nt < 4; ++nt) {
    int c = bn*128 + wn + nt*16 + (l & 15);
    float bv = bias0[c];
    if (TWOBIAS) bv += bias1[c];
    #pragma unroll
    for (int mt = 0; mt < 4; ++mt) {
      #pragma unroll
      for (int j = 0; j < 4; ++j) {
        int r = bm*128 + wm + mt*16 + ((l >> 4) << 2) + j;
        float v = acc[mt][nt][j] + bv;
        if (RELU) v = fmaxf(v, 0.f);
        if (BF16OUT) Cb[(size_t)r * N + c] = (__bf16)v;
        else         Cf[(size_t)r * N + c] = v;
      }
    }
  }
}

// ---------------------------------------------------------------- LSTM scan chunk
// 16 persistent WGs. H exchange via self-validating 8B packets:
//   packet = (hi32 = step tag, lo32 = 2 x bf16 h payload), relaxed agent-scope atomics.
// The tag rides WITH the data -> one cross-XCD hop per step (no flag hop, no release barrier).
// Double-buffered by step parity; safety: a WG stores tag t+2 into buf[(t+1)&1] only after
// consuming all 16 slices tagged t+1, which certifies every WG finished reading that buffer.
__global__ __launch_bounds__(512) void lstm_scan(
    const __bf16* __restrict__ Whh,      // [2048][512] bf16
    const __bf16* __restrict__ preC,     // [RCH_][2048] bf16 (chunk-local rows)
    const float*  __restrict__ x,        // residual (global rows)
    const void*   __restrict__ firstp,
    const float*  __restrict__ h0,
    const float*  __restrict__ c0,
    float*        __restrict__ cstate,   // [B_*D_] f32 (pre-multiplied by keep), carries c across chunks
    __bf16*       __restrict__ ymidbC,   // [RCH_][512] bf16 (chunk-local rows)
    unsigned long long* __restrict__ HP, // [2][8192] packets
    const unsigned int* __restrict__ modep,
    float* __restrict__ hout, float* __restrict__ cout,
    int tBase){
  const int s = blockIdx.x, tid = threadIdx.x, w = tid >> 6, l = tid & 63;
  const int d0 = s * 32;
  __shared__ __bf16 Hl[32 * 520];      // staged H [batch][dim], stride-padded + XOR swizzle
  __shared__ float  gl[32 * 130];      // gate exchange [batch][gate_row_local], padded
  const int mode = (int)*modep;

  // Whh B-fragments resident in VGPRs: wave w owns gate rows rl = w*16 + (l&15)
  bf16x8 wf[16];
  {
    int rl = w*16 + (l & 15);
    int gr = (rl >> 5) * 512 + d0 + (rl & 31);     // PyTorch gate order i,f,g,o
    const __bf16* base = Whh + (size_t)gr * 512 + ((l >> 4) << 3);
    #pragma unroll
    for (int kt = 0; kt < 16; ++kt) wf[kt] = *(const bf16x8*)(void*)(base + kt*32);
  }
  const int b = tid >> 4, dl2 = (tid & 15) * 2;    // producer role: (batch, dim pair)
  const int dg = d0 + dl2;
  const int opid = b * 256 + s * 16 + (tid & 15);  // own packet id
  const int sb = tid >> 4, ss = tid & 15;          // staging role: batch sb, source slice ss
  const int pid0 = sb * 256 + ss * 16;             // 16 packets, 128B contiguous

  float cr[2];
  if (tBase == 0) {
    float k0 = firstval(firstp, mode, b) ? 0.f : 1.f;
    float2 c2 = *(const float2*)(c0 + (size_t)b*512 + dg);
    cr[0] = c2.x * k0; cr[1] = c2.y * k0;
    float2 h = *(const float2*)(h0 + (size_t)b*512 + dg);
    unsigned long long pkt = (1ULL << 32) | (unsigned long long)pack2bf(h.x*k0, h.y*k0);
    __hip_atomic_store(HP + opid, pkt, __ATOMIC_RELAXED, __HIP_MEMORY_SCOPE_AGENT);
  } else {
    float2 c2 = *(const float2*)(cstate + (size_t)b*512 + dg);
    cr[0] = c2.x; cr[1] = c2.y;
  }

  for (int tl = 0; tl < TCH_; ++tl) {
    const int t = tBase + tl;
    const int rowg = t * 32 + b, rowl = tl * 32 + b;
    // prefetch (overlaps the poll below)
    unsigned int pg[4];
    #pragma unroll
    for (int gi = 0; gi < 4; ++gi)
      pg[gi] = *(const unsigned int*)(void*)(preC + (size_t)rowl * 2048 + gi*512 + dg);
    float2 xv = *(const float2*)(x + (size_t)rowg * 512 + dg);
    const bool f_t1 = (t < T_-1) ? firstval(firstp, mode, rowg + 32) : false;

    // ---- poll+stage: issue all 16 packet loads in parallel, batch-reload stale ones
    const unsigned want = (unsigned)(t + 1);
    const unsigned long long* Pb = HP + ((size_t)(t & 1) << 13);
    unsigned long long pk[16];
    #pragma unroll
    for (int j = 0; j < 16; ++j)
      pk[j] = __hip_atomic_load(Pb + pid0 + j, __ATOMIC_RELAXED, __HIP_MEMORY_SCOPE_AGENT);
    while (true) {
      unsigned stale = 0;
      #pragma unroll
      for (int j = 0; j < 16; ++j)
        if ((unsigned)(pk[j] >> 32) != want) stale |= (1u << j);
      if (!stale) break;
      __builtin_amdgcn_s_sleep(1);
      #pragma unroll
      for (int j = 0; j < 16; ++j)
        if (stale & (1u << j))
          pk[j] = __hip_atomic_load(Pb + pid0 + j, __ATOMIC_RELAXED, __HIP_MEMORY_SCOPE_AGENT);
    }
    // payloads -> LDS (4 x 16B writes; dims ss*32..+31 of batch sb)
    #pragma unroll
    for (int j4 = 0; j4 < 4; ++j4) {
      uint4 pay;
      pay.x = (unsigned)pk[j4*4+0]; pay.y = (unsigned)pk[j4*4+1];
      pay.z = (unsigned)pk[j4*4+2]; pay.w = (unsigned)pk[j4*4+3];
      int ke = ss*32 + j4*8;
      int di = sb*520 + (ke ^ ((sb & 7) << 3));
      *(uint4*)(void*)(Hl + di) = pay;
    }
    __syncthreads();

    // ---- gates[b, rl] = H @ Whh_slice^T
    f32x4 acc0 = (f32x4){0.f,0.f,0.f,0.f}, acc1 = (f32x4){0.f,0.f,0.f,0.f};
    #pragma unroll
    for (int kt = 0; kt < 16; ++kt) {
      int ke = kt*32 + ((l >> 4) << 3);
      int r0 = (l & 15), r1 = 16 + (l & 15);
      bf16x8 a0 = *(const bf16x8*)(void*)(Hl + r0*520 + (ke ^ ((r0 & 7) << 3)));
      bf16x8 a1 = *(const bf16x8*)(void*)(Hl + r1*520 + (ke ^ ((r1 & 7) << 3)));
      acc0 = __builtin_amdgcn_mfma_f32_16x16x32_bf16(a0, wf[kt], acc0, 0, 0, 0);
      acc1 = __builtin_amdgcn_mfma_f32_16x16x32_bf16(a1, wf[kt], acc1, 0, 0, 0);
    }
    // ---- gate exchange through LDS
    {
      int col = w*16 + (l & 15);
      #pragma unroll
      for (int j = 0; j < 4; ++j) {
        gl[(((l >> 4) << 2) + j) * 130 + col]        = acc0[j];
        gl[((16 + ((l >> 4) << 2) + j)) * 130 + col] = acc1[j];
      }
    }
    __syncthreads();

    // ---- cell update for (b, dg), (b, dg+1); cr pre-multiplied by keep(first[t])
    float2 gv[4];
    #pragma unroll
    for (int gi = 0; gi < 4; ++gi) gv[gi] = *(const float2*)(gl + b*130 + gi*32 + dl2);
    const float keep1 = f_t1 ? 0.f : 1.f;
    float hh[2], cc[2];
    #pragma unroll
    for (int p = 0; p < 2; ++p) {
      float gi_ = (p ? gv[0].y : gv[0].x) + (p ? bfhi(pg[0]) : bflo(pg[0]));
      float gf_ = (p ? gv[1].y : gv[1].x) + (p ? bfhi(pg[1]) : bflo(pg[1]));
      float gg_ = (p ? gv[2].y : gv[2].x) + (p ? bfhi(pg[2]) : bflo(pg[2]));
      float go_ = (p ? gv[3].y : gv[3].x) + (p ? bfhi(pg[3]) : bflo(pg[3]));
      float cn = sigm(gf_) * cr[p] + sigm(gi_) * tanh_(gg_);
      float h  = sigm(go_) * tanh_(cn);
      cc[p] = cn; hh[p] = h;
    }
    cr[0] = cc[0] * keep1; cr[1] = cc[1] * keep1;
    float2 yv = { hh[0] + xv.x, hh[1] + xv.y };
    if (t < T_-1) {
      // publish own packet for H_{t+1} (tag t+2) -- this IS the release
      unsigned long long pkt = (((unsigned long long)(unsigned)(t + 2)) << 32)
                             | (unsigned long long)pack2bf(hh[0]*keep1, hh[1]*keep1);
      __hip_atomic_store(HP + (((size_t)((t+1) & 1)) << 13) + opid, pkt,
                         __ATOMIC_RELAXED, __HIP_MEMORY_SCOPE_AGENT);
      if (tl == TCH_-1) *(float2*)(cstate + (size_t)b*512 + dg) = make_float2(cr[0], cr[1]);
    } else {
      *(float2*)(hout + (size_t)b*512 + dg) = make_float2(hh[0], hh[1]);
      *(float2*)(cout + (size_t)b*512 + dg) = make_float2(cc[0], cc[1]);
    }
    // end-of-iter barrier: protects Hl/gl reuse across iterations (cell reads done before
    // next staging writes). Packet store issued before it so the release drains here.
    __syncthreads();
    // deferred output store (off the critical path; drains under next step's poll)
    *(unsigned int*)(void*)(ymidbC + (size_t)rowl * 512 + dg) = pack2bf(yv.x, yv.y);
  }
}

// ---------------------------------------------------------------- fused adapter + final residual (in-place on y2)
__global__ __launch_bounds__(256) void adapter_out_kernel(
    float* __restrict__ y2,              // [RCH_][512] in/out (lives in d_out)
    const __bf16* __restrict__ ymidb,    // [RCH_][512]
    const __bf16* __restrict__ awT0,     // [512][64] = aw0^T
    const __bf16* __restrict__ awT1,     // [64][512] = aw1^T
    const float* __restrict__ ab0, const float* __restrict__ ab1){
  __shared__ float zl[16 * 64];
  const int w = threadIdx.x >> 6, l = threadIdx.x & 63;
  const int r0 = blockIdx.x * 16;
  const float bz = ab0[l];
  #pragma unroll
  for (int rr = 0; rr < 4; ++rr) {
    int rowl = w*4 + rr;
    const float* yr = y2 + (size_t)(r0 + rowl) * 512;
    float acc = bz;
    #pragma unroll 4
    for (int k = 0; k < 512; ++k) acc += yr[k] * (float)awT0[k*64 + l];
    zl[rowl*64 + l] = fmaxf(acc, 0.f);
  }
  __syncthreads();
  #pragma unroll
  for (int rr = 0; rr < 4; ++rr) {
    int rowl = w*4 + rr; int row = r0 + rowl;
    const float* yr = y2  + (size_t)row * 512;
    const __bf16* mr = ymidb + (size_t)row * 512;
    #pragma unroll
    for (int dd = 0; dd < 8; ++dd) {
      int d = dd*64 + l;
      float acc = ab1[d] + yr[d] + (float)mr[d];
      #pragma unroll 4
      for (int j = 0; j < 64; ++j) acc += zl[rowl*64 + j] * (float)awT1[j*512 + d];
      y2[(size_t)row * 512 + d] = acc;
    }
  }
}

// ---------------------------------------------------------------- launch
extern "C" void kernel_launch(void* const* d_in, const int* in_sizes, int n_in,
                              void* d_out, int out_size, void* d_ws, size_t ws_size,
                              hipStream_t stream){
  (void)in_sizes; (void)n_in; (void)out_size; (void)ws_size;
  const float* x    = (const float*)d_in[0];
  const void*  first=               d_in[1];
  const float* h0   = (const float*)d_in[2];
  const float* c0   = (const float*)d_in[3];
  const float* ln_g = (const float*)d_in[4];
  const float* ln_b = (const float*)d_in[5];
  const float* Wih  = (const float*)d_in[6];
  const float* Whh  = (const float*)d_in[7];
  const float* bih  = (const float*)d_in[8];
  const float* bhh  = (const float*)d_in[9];
  const float* m0w  = (const float*)d_in[10];
  const float* m0b  = (const float*)d_in[11];
  const float* m1w  = (const float*)d_in[12];
  const float* m1b  = (const float*)d_in[13];
  const float* aw0  = (const float*)d_in[14];
  const float* ab0  = (const float*)d_in[15];
  const float* aw1  = (const float*)d_in[16];
  const float* ab1  = (const float*)d_in[17];

  // workspace layout — total ~59.1 MB
  char* ws = (char*)d_ws;
  __bf16* buf0  = (__bf16*)(ws + 0LL);            // 32 MB: preC, later a1C (disjoint lifetimes per chunk)
  __bf16* xnbfC = (__bf16*)(ws + 33554432LL);     // 8 MB
  __bf16* ymidbC= (__bf16*)(ws + 41943040LL);     // 8 MB
  __bf16* wihb  = (__bf16*)(ws + 50331648LL);     // 2 MB
  __bf16* whhb  = (__bf16*)(ws + 52428800LL);     // 2 MB
  __bf16* m0bf  = (__bf16*)(ws + 54525952LL);     // 2 MB
  __bf16* m1bf  = (__bf16*)(ws + 56623104LL);     // 2 MB
  __bf16* awT0  = (__bf16*)(ws + 58720256LL);     // 64 KB
  __bf16* awT1  = (__bf16*)(ws + 58785792LL);     // 64 KB
  unsigned long long* HP = (unsigned long long*)(ws + 58851328LL);  // 128 KB packet buffers
  float*  cstate= (float*) (ws + 58982400LL);     // 64 KB
  unsigned int* mode = (unsigned int*)(ws + 59047936LL);
  __bf16* preC = buf0;
  __bf16* a1C  = buf0;

  float* out  = (float*)d_out;
  float* hout = out + (size_t)TB_ * D_;
  float* cout = hout + B_ * D_;

  // zero packet tags: kills cross-replay stale-tag aliasing (buf0 ends at tag 1023,
  // which a t=1022 consumer of the NEXT replay would otherwise accept)
  hipMemsetAsync(HP, 0, 131072, stream);
  detect_first_kernel<<<1, 256, 0, stream>>>((const unsigned char*)first, mode);
  convert_w_kernel<<<4352, 256, 0, stream>>>(Wih, Whh, m0w, m1w, aw0, aw1,
                                             wihb, whhb, m0bf, m1bf, awT0, awT1);
  for (int c = 0; c < 4; ++c) {
    const size_t ro = (size_t)c * RCH_;
    ln_kernel<<<RCH_/4, 256, 0, stream>>>(x + ro * D_, ln_g, ln_b, xnbfC);
    gemm_bt<0,1,1><<<dim3(RCH_/128, FF_/128), 256, 0, stream>>>(xnbfC, wihb, bih, bhh,
                                                                nullptr, preC, RCH_, 2048, 512);
    lstm_scan<<<16, 512, 0, stream>>>(whhb, preC, x, first, h0, c0, cstate, ymidbC,
                                      HP, mode, hout, cout, c * TCH_);
    gemm_bt<1,1,0><<<dim3(RCH_/128, FF_/128), 256, 0, stream>>>(ymidbC, m0bf, m0b, nullptr,
                                                                nullptr, a1C, RCH_, FF_, 512);
    gemm_bt<0,0,0><<<dim3(RCH_/128, D_/128), 256, 0, stream>>>(a1C, m1bf, m1b, nullptr,
                                                               out + ro * D_, nullptr, RCH_, D_, FF_);
    adapter_out_kernel<<<RCH_/16, 256, 0, stream>>>(out + ro * D_, ymidbC, awT0, awT1, ab0, ab1);
  }
}

// Round 6
// 5377.621 us; speedup vs baseline: 3.2335x; 1.8713x over previous
//
#include <hip/hip_runtime.h>

#define T_ 1024
#define B_ 32
#define D_ 512
#define FF_ 2048
#define TB_ 32768   // T_*B_
#define TCH_ 256    // T chunk
#define RCH_ 8192   // TCH_*B_ rows per chunk

typedef short bf16x8 __attribute__((ext_vector_type(8)));
typedef float f32x4 __attribute__((ext_vector_type(4)));

static __device__ __forceinline__ unsigned int pack2bf(float a, float b){
  union { __bf16 h[2]; unsigned int u; } z;
  z.h[0] = (__bf16)a; z.h[1] = (__bf16)b; return z.u;
}
static __device__ __forceinline__ float bflo(unsigned int u){ return __uint_as_float(u<<16); }
static __device__ __forceinline__ float bfhi(unsigned int u){ return __uint_as_float(u & 0xffff0000u); }
static __device__ __forceinline__ float sigm(float x){ return 1.f/(1.f+__expf(-x)); }
static __device__ __forceinline__ float tanh_(float x){ return 1.f - 2.f/(1.f+__expf(2.f*x)); }

// first[] may be uint8 (numpy bool) or int32; detected at runtime.
static __device__ __forceinline__ bool firstval(const void* p, int mode, int idx){
  return mode ? (((const int*)p)[idx] != 0) : (((const unsigned char*)p)[idx] != 0);
}

// ---------------------------------------------------------------- detect bool dtype
__global__ void detect_first_kernel(const unsigned char* __restrict__ p, unsigned int* __restrict__ mode){
  __shared__ int found;
  if (threadIdx.x == 0) found = 0;
  __syncthreads();
  int f = 0;
  for (int i = threadIdx.x; i < TB_; i += 256) if ((i & 3) != 0 && p[i] != 0) f = 1;
  if (f) atomicAdd(&found, 1);
  __syncthreads();
  if (threadIdx.x == 0) *mode = (found == 0) ? 1u : 0u;   // 1 => int32, 0 => uint8
}

// ---------------------------------------------------------------- weight conversion
__global__ void convert_w_kernel(const float* __restrict__ Wih, const float* __restrict__ Whh,
                                 const float* __restrict__ m0w, const float* __restrict__ m1w,
                                 const float* __restrict__ aw0, const float* __restrict__ aw1,
                                 __bf16* __restrict__ Wihb, __bf16* __restrict__ Whhb,
                                 __bf16* __restrict__ m0b,  __bf16* __restrict__ m1b,
                                 __bf16* __restrict__ awT0, __bf16* __restrict__ awT1){
  int bid = blockIdx.x;
  if (bid < 4096) {
    int ai = bid >> 10;
    size_t off = (size_t)(bid & 1023) * 1024 + threadIdx.x * 4;
    const float* src = (ai==0)?Wih:(ai==1)?Whh:(ai==2)?m0w:m1w;
    __bf16* dst = (ai==0)?Wihb:(ai==1)?Whhb:(ai==2)?m0b:m1b;
    float4 v = *(const float4*)(src + off);
    union { __bf16 h[4]; uint2 u; } z;
    z.h[0]=(__bf16)v.x; z.h[1]=(__bf16)v.y; z.h[2]=(__bf16)v.z; z.h[3]=(__bf16)v.w;
    *(uint2*)(void*)(dst + off) = z.u;
  } else {
    int e = (bid - 4096) * 256 + threadIdx.x;      // 0..65535
    if (e < 32768) { int k = e >> 6, j = e & 63;  awT0[e] = (__bf16)aw0[j*512 + k]; }
    else { int e2 = e - 32768; int j = e2 >> 9, d = e2 & 511; awT1[e2] = (__bf16)aw1[d*64 + j]; }
  }
}

// ---------------------------------------------------------------- layernorm -> bf16 (chunk of 8192 rows)
__global__ __launch_bounds__(256) void ln_kernel(const float* __restrict__ x,
                                                 const float* __restrict__ g, const float* __restrict__ b,
                                                 __bf16* __restrict__ xn){
  const int w = threadIdx.x >> 6, l = threadIdx.x & 63;
  const int row = blockIdx.x * 4 + w;
  const float* xr = x + (size_t)row * D_;
  const int e0 = l * 4, e1 = 256 + l * 4;
  float4 v0 = *(const float4*)(xr + e0);
  float4 v1 = *(const float4*)(xr + e1);
  float s  = v0.x+v0.y+v0.z+v0.w + v1.x+v1.y+v1.z+v1.w;
  float s2 = v0.x*v0.x+v0.y*v0.y+v0.z*v0.z+v0.w*v0.w + v1.x*v1.x+v1.y*v1.y+v1.z*v1.z+v1.w*v1.w;
  #pragma unroll
  for (int off = 1; off < 64; off <<= 1) { s += __shfl_xor(s, off); s2 += __shfl_xor(s2, off); }
  float mu = s * (1.f/512.f);
  float var = s2 * (1.f/512.f) - mu*mu;
  float rstd = rsqrtf(var + 1e-5f);
  float4 g0 = *(const float4*)(g + e0), g1 = *(const float4*)(g + e1);
  float4 b0 = *(const float4*)(b + e0), b1 = *(const float4*)(b + e1);
  union { __bf16 h[4]; uint2 u; } o0, o1;
  o0.h[0]=(__bf16)((v0.x-mu)*rstd*g0.x+b0.x); o0.h[1]=(__bf16)((v0.y-mu)*rstd*g0.y+b0.y);
  o0.h[2]=(__bf16)((v0.z-mu)*rstd*g0.z+b0.z); o0.h[3]=(__bf16)((v0.w-mu)*rstd*g0.w+b0.w);
  o1.h[0]=(__bf16)((v1.x-mu)*rstd*g1.x+b1.x); o1.h[1]=(__bf16)((v1.y-mu)*rstd*g1.y+b1.y);
  o1.h[2]=(__bf16)((v1.z-mu)*rstd*g1.z+b1.z); o1.h[3]=(__bf16)((v1.w-mu)*rstd*g1.w+b1.w);
  *(uint2*)(void*)(xn + (size_t)row * D_ + e0) = o0.u;
  *(uint2*)(void*)(xn + (size_t)row * D_ + e1) = o1.u;
}

// ---------------------------------------------------------------- bf16 "BT" GEMM  C[M,N] = A[M,K] @ W[N,K]^T + bias
template<int RELU, int BF16OUT, int TWOBIAS>
__global__ __launch_bounds__(256) void gemm_bt(const __bf16* __restrict__ A, const __bf16* __restrict__ W,
                                               const float* __restrict__ bias0, const float* __restrict__ bias1,
                                               float* __restrict__ Cf, __bf16* __restrict__ Cb,
                                               int M, int N, int K){
  __shared__ __bf16 As[128*64];
  __shared__ __bf16 Bs[128*64];
  const int tid = threadIdx.x, w = tid >> 6, l = tid & 63;
  const int bm = blockIdx.x, bn = blockIdx.y;
  const int wm = (w >> 1) * 64, wn = (w & 1) * 64;
  const int nk = K >> 6;

  uint4 ra[4], rb[4];
  #pragma unroll
  for (int i = 0; i < 4; ++i) {
    int s = tid + (i << 8); int row = s >> 3; int ks = s & 7;
    ra[i] = *(const uint4*)(void*)(A + (size_t)(bm*128 + row) * K + ks*8);
    rb[i] = *(const uint4*)(void*)(W + (size_t)(bn*128 + row) * K + ks*8);
  }
  f32x4 acc[4][4];
  #pragma unroll
  for (int mt = 0; mt < 4; ++mt)
    #pragma unroll
    for (int nt = 0; nt < 4; ++nt) acc[mt][nt] = (f32x4){0.f,0.f,0.f,0.f};

  for (int kt = 0; kt < nk; ++kt) {
    __syncthreads();
    #pragma unroll
    for (int i = 0; i < 4; ++i) {
      int s = tid + (i << 8); int row = s >> 3; int ks = s & 7;
      int wi = row * 64 + ((ks * 8) ^ ((row & 7) << 3));   // XOR swizzle (elements)
      *(uint4*)(void*)(As + wi) = ra[i];
      *(uint4*)(void*)(Bs + wi) = rb[i];
    }
    __syncthreads();
    if (kt + 1 < nk) {
      #pragma unroll
      for (int i = 0; i < 4; ++i) {
        int s = tid + (i << 8); int row = s >> 3; int ks = s & 7;
        ra[i] = *(const uint4*)(void*)(A + (size_t)(bm*128 + row) * K + (kt+1)*64 + ks*8);
        rb[i] = *(const uint4*)(void*)(W + (size_t)(bn*128 + row) * K + (kt+1)*64 + ks*8);
      }
    }
    #pragma unroll
    for (int kk = 0; kk < 2; ++kk) {
      bf16x8 af[4], bfv[4];
      const int ke = kk * 32 + ((l >> 4) << 3);
      #pragma unroll
      for (int mt = 0; mt < 4; ++mt) {
        int row = wm + mt*16 + (l & 15);
        af[mt] = *(const bf16x8*)(void*)(As + row*64 + (ke ^ ((row & 7) << 3)));
      }
      #pragma unroll
      for (int nt = 0; nt < 4; ++nt) {
        int row = wn + nt*16 + (l & 15);
        bfv[nt] = *(const bf16x8*)(void*)(Bs + row*64 + (ke ^ ((row & 7) << 3)));
      }
      #pragma unroll
      for (int mt = 0; mt < 4; ++mt)
        #pragma unroll
        for (int nt = 0; nt < 4; ++nt)
          acc[mt][nt] = __builtin_amdgcn_mfma_f32_16x16x32_bf16(af[mt], bfv[nt], acc[mt][nt], 0, 0, 0);
    }
  }
  // epilogue: D row = (l>>4)*4+j, col = l&15 (m89-verified layout)
  #pragma unroll
  for (int nt = 0; nt < 4; ++nt) {
    int c = bn*128 + wn + nt*16 + (l & 15);
    float bv = bias0[c];
    if (TWOBIAS) bv += bias1[c];
    #pragma unroll
    for (int mt = 0; mt < 4; ++mt) {
      #pragma unroll
      for (int j = 0; j < 4; ++j) {
        int r = bm*128 + wm + mt*16 + ((l >> 4) << 2) + j;
        float v = acc[mt][nt][j] + bv;
        if (RELU) v = fmaxf(v, 0.f);
        if (BF16OUT) Cb[(size_t)r * N + c] = (__bf16)v;
        else         Cf[(size_t)r * N + c] = v;
      }
    }
  }
}

// ---------------------------------------------------------------- LSTM scan chunk
// 16 persistent WGs. H exchange via self-validating 8B packets
//   (hi32 = step tag, lo32 = 2 x bf16 payload), relaxed agent-scope atomics: one hop/step.
// Packet loads are lane-coalesced (tid + j*512); LDS slot derived from packet id.
// Double-buffered by parity; producer overwrites buf[(t+1)&1] only after consuming all
// tags t+1, certifying every WG finished reading it.
__global__ __launch_bounds__(512) void lstm_scan(
    const __bf16* __restrict__ Whh,      // [2048][512] bf16
    const __bf16* __restrict__ preC,     // [RCH_][2048] bf16 (chunk-local rows)
    const float*  __restrict__ x,        // residual (global rows)
    const void*   __restrict__ firstp,
    const float*  __restrict__ h0,
    const float*  __restrict__ c0,
    float*        __restrict__ cstate,   // [B_*D_] f32 (pre-multiplied by keep)
    __bf16*       __restrict__ ymidbC,   // [RCH_][512] bf16 (chunk-local rows)
    unsigned long long* __restrict__ HP, // [2][8192] packets
    const unsigned int* __restrict__ modep,
    float* __restrict__ hout, float* __restrict__ cout,
    int tBase){
  const int s = blockIdx.x, tid = threadIdx.x, w = tid >> 6, l = tid & 63;
  const int d0 = s * 32;
  __shared__ __bf16 Hl[32 * 512];      // staged H, stride 512 + XOR swizzle (2-way max)
  __shared__ float  gl[32 * 132];      // gate exchange, stride 132 (2-way max)
  const int mode = (int)*modep;

  // Whh B-fragments resident in VGPRs: wave w owns gate rows rl = w*16 + (l&15)
  bf16x8 wf[16];
  {
    int rl = w*16 + (l & 15);
    int gr = (rl >> 5) * 512 + d0 + (rl & 31);     // PyTorch gate order i,f,g,o
    const __bf16* base = Whh + (size_t)gr * 512 + ((l >> 4) << 3);
    #pragma unroll
    for (int kt = 0; kt < 16; ++kt) wf[kt] = *(const bf16x8*)(void*)(base + kt*32);
  }
  const int b = tid >> 4, dl2 = (tid & 15) * 2;    // producer role: (batch, dim pair)
  const int dg = d0 + dl2;
  const int opid = b * 256 + s * 16 + (tid & 15);  // own packet id

  float cr[2];
  if (tBase == 0) {
    float k0 = firstval(firstp, mode, b) ? 0.f : 1.f;
    float2 c2 = *(const float2*)(c0 + (size_t)b*512 + dg);
    cr[0] = c2.x * k0; cr[1] = c2.y * k0;
    float2 h = *(const float2*)(h0 + (size_t)b*512 + dg);
    unsigned long long pkt = (1ULL << 32) | (unsigned long long)pack2bf(h.x*k0, h.y*k0);
    __hip_atomic_store(HP + opid, pkt, __ATOMIC_RELAXED, __HIP_MEMORY_SCOPE_AGENT);
  } else {
    float2 c2 = *(const float2*)(cstate + (size_t)b*512 + dg);
    cr[0] = c2.x; cr[1] = c2.y;
  }

  for (int tl = 0; tl < TCH_; ++tl) {
    const int t = tBase + tl;
    const int rowg = t * 32 + b, rowl = tl * 32 + b;
    // prefetch (overlaps the poll below)
    unsigned int pg[4];
    #pragma unroll
    for (int gi = 0; gi < 4; ++gi)
      pg[gi] = *(const unsigned int*)(void*)(preC + (size_t)rowl * 2048 + gi*512 + dg);
    float2 xv = *(const float2*)(x + (size_t)rowg * 512 + dg);
    const bool f_t1 = (t < T_-1) ? firstval(firstp, mode, rowg + 32) : false;

    // ---- poll: COALESCED packet loads (thread tid owns pids {tid + j*512})
    const unsigned want = (unsigned)(t + 1);
    const unsigned long long* Pb = HP + ((size_t)(t & 1) << 13);
    unsigned long long pk[16];
    #pragma unroll
    for (int j = 0; j < 16; ++j)
      pk[j] = __hip_atomic_load(Pb + tid + (j << 9), __ATOMIC_RELAXED, __HIP_MEMORY_SCOPE_AGENT);
    while (true) {
      unsigned stale = 0;
      #pragma unroll
      for (int j = 0; j < 16; ++j)
        if ((unsigned)(pk[j] >> 32) != want) stale |= (1u << j);
      if (!stale) break;
      __builtin_amdgcn_s_sleep(1);
      #pragma unroll
      for (int j = 0; j < 16; ++j)
        if (stale & (1u << j))
          pk[j] = __hip_atomic_load(Pb + tid + (j << 9), __ATOMIC_RELAXED, __HIP_MEMORY_SCOPE_AGENT);
    }
    // payloads -> LDS: pid = b*256 + s*16 + i  ->  row b, elems s*32 + i*2 (XOR-swizzled)
    #pragma unroll
    for (int j = 0; j < 16; ++j) {
      int pid = tid + (j << 9);
      int pb = pid >> 8, ps = (pid >> 4) & 15, pi = pid & 15;
      int q = ps*32 + pi*2;
      *(unsigned int*)(void*)(Hl + pb*512 + (q ^ ((pb & 7) << 3))) = (unsigned)pk[j];
    }
    __syncthreads();

    // ---- gates[b, rl] = H @ Whh_slice^T  (2 interleaved chains per acc, 8-deep)
    f32x4 a0a = (f32x4){0.f,0.f,0.f,0.f}, a0b = (f32x4){0.f,0.f,0.f,0.f};
    f32x4 a1a = (f32x4){0.f,0.f,0.f,0.f}, a1b = (f32x4){0.f,0.f,0.f,0.f};
    #pragma unroll
    for (int kt = 0; kt < 16; kt += 2) {
      int ke0 = kt*32 + ((l >> 4) << 3), ke1 = (kt+1)*32 + ((l >> 4) << 3);
      int r0 = (l & 15), r1 = 16 + (l & 15);
      bf16x8 h00 = *(const bf16x8*)(void*)(Hl + r0*512 + (ke0 ^ ((r0 & 7) << 3)));
      bf16x8 h01 = *(const bf16x8*)(void*)(Hl + r0*512 + (ke1 ^ ((r0 & 7) << 3)));
      bf16x8 h10 = *(const bf16x8*)(void*)(Hl + r1*512 + (ke0 ^ ((r1 & 7) << 3)));
      bf16x8 h11 = *(const bf16x8*)(void*)(Hl + r1*512 + (ke1 ^ ((r1 & 7) << 3)));
      a0a = __builtin_amdgcn_mfma_f32_16x16x32_bf16(h00, wf[kt],   a0a, 0, 0, 0);
      a0b = __builtin_amdgcn_mfma_f32_16x16x32_bf16(h01, wf[kt+1], a0b, 0, 0, 0);
      a1a = __builtin_amdgcn_mfma_f32_16x16x32_bf16(h10, wf[kt],   a1a, 0, 0, 0);
      a1b = __builtin_amdgcn_mfma_f32_16x16x32_bf16(h11, wf[kt+1], a1b, 0, 0, 0);
    }
    f32x4 acc0 = a0a + a0b, acc1 = a1a + a1b;
    // ---- gate exchange through LDS (stride 132: 2-way max both sides)
    {
      int col = w*16 + (l & 15);
      #pragma unroll
      for (int j = 0; j < 4; ++j) {
        gl[(((l >> 4) << 2) + j) * 132 + col]        = acc0[j];
        gl[((16 + ((l >> 4) << 2) + j)) * 132 + col] = acc1[j];
      }
    }
    __syncthreads();

    // ---- cell update for (b, dg), (b, dg+1); cr pre-multiplied by keep(first[t])
    float2 gv[4];
    #pragma unroll
    for (int gi = 0; gi < 4; ++gi) gv[gi] = *(const float2*)(gl + b*132 + gi*32 + dl2);
    const float keep1 = f_t1 ? 0.f : 1.f;
    float hh[2], cc[2];
    #pragma unroll
    for (int p = 0; p < 2; ++p) {
      float gi_ = (p ? gv[0].y : gv[0].x) + (p ? bfhi(pg[0]) : bflo(pg[0]));
      float gf_ = (p ? gv[1].y : gv[1].x) + (p ? bfhi(pg[1]) : bflo(pg[1]));
      float gg_ = (p ? gv[2].y : gv[2].x) + (p ? bfhi(pg[2]) : bflo(pg[2]));
      float go_ = (p ? gv[3].y : gv[3].x) + (p ? bfhi(pg[3]) : bflo(pg[3]));
      float cn = sigm(gf_) * cr[p] + sigm(gi_) * tanh_(gg_);
      float h  = sigm(go_) * tanh_(cn);
      cc[p] = cn; hh[p] = h;
    }
    cr[0] = cc[0] * keep1; cr[1] = cc[1] * keep1;
    float2 yv = { hh[0] + xv.x, hh[1] + xv.y };
    if (t < T_-1) {
      // publish own packet for H_{t+1} (tag t+2) -- this IS the release (payload rides with tag)
      unsigned long long pkt = (((unsigned long long)(unsigned)(t + 2)) << 32)
                             | (unsigned long long)pack2bf(hh[0]*keep1, hh[1]*keep1);
      __hip_atomic_store(HP + (((size_t)((t+1) & 1)) << 13) + opid, pkt,
                         __ATOMIC_RELAXED, __HIP_MEMORY_SCOPE_AGENT);
      if (tl == TCH_-1) *(float2*)(cstate + (size_t)b*512 + dg) = make_float2(cr[0], cr[1]);
    } else {
      *(float2*)(hout + (size_t)b*512 + dg) = make_float2(hh[0], hh[1]);
      *(float2*)(cout + (size_t)b*512 + dg) = make_float2(cc[0], cc[1]);
    }
    // NOTE: no end-of-iter barrier. Next iteration's post-stage __syncthreads orders
    // this step's gl/Hl reads against next step's LDS writes (all reads precede the
    // poll, which precedes the staging writes; barrier certifies all threads passed).
    *(unsigned int*)(void*)(ymidbC + (size_t)rowl * 512 + dg) = pack2bf(yv.x, yv.y);
  }
}

// ---------------------------------------------------------------- fused adapter + final residual (in-place on y2)
__global__ __launch_bounds__(256) void adapter_out_kernel(
    float* __restrict__ y2,              // [RCH_][512] in/out (lives in d_out)
    const __bf16* __restrict__ ymidb,    // [RCH_][512]
    const __bf16* __restrict__ awT0,     // [512][64] = aw0^T
    const __bf16* __restrict__ awT1,     // [64][512] = aw1^T
    const float* __restrict__ ab0, const float* __restrict__ ab1){
  __shared__ float zl[16 * 64];
  const int w = threadIdx.x >> 6, l = threadIdx.x & 63;
  const int r0 = blockIdx.x * 16;
  const float bz = ab0[l];
  #pragma unroll
  for (int rr = 0; rr < 4; ++rr) {
    int rowl = w*4 + rr;
    const float* yr = y2 + (size_t)(r0 + rowl) * 512;
    float acc = bz;
    #pragma unroll 4
    for (int k = 0; k < 512; ++k) acc += yr[k] * (float)awT0[k*64 + l];
    zl[rowl*64 + l] = fmaxf(acc, 0.f);
  }
  __syncthreads();
  #pragma unroll
  for (int rr = 0; rr < 4; ++rr) {
    int rowl = w*4 + rr; int row = r0 + rowl;
    const float* yr = y2  + (size_t)row * 512;
    const __bf16* mr = ymidb + (size_t)row * 512;
    #pragma unroll
    for (int dd = 0; dd < 8; ++dd) {
      int d = dd*64 + l;
      float acc = ab1[d] + yr[d] + (float)mr[d];
      #pragma unroll 4
      for (int j = 0; j < 64; ++j) acc += zl[rowl*64 + j] * (float)awT1[j*512 + d];
      y2[(size_t)row * 512 + d] = acc;
    }
  }
}

// ---------------------------------------------------------------- launch
extern "C" void kernel_launch(void* const* d_in, const int* in_sizes, int n_in,
                              void* d_out, int out_size, void* d_ws, size_t ws_size,
                              hipStream_t stream){
  (void)in_sizes; (void)n_in; (void)out_size; (void)ws_size;
  const float* x    = (const float*)d_in[0];
  const void*  first=               d_in[1];
  const float* h0   = (const float*)d_in[2];
  const float* c0   = (const float*)d_in[3];
  const float* ln_g = (const float*)d_in[4];
  const float* ln_b = (const float*)d_in[5];
  const float* Wih  = (const float*)d_in[6];
  const float* Whh  = (const float*)d_in[7];
  const float* bih  = (const float*)d_in[8];
  const float* bhh  = (const float*)d_in[9];
  const float* m0w  = (const float*)d_in[10];
  const float* m0b  = (const float*)d_in[11];
  const float* m1w  = (const float*)d_in[12];
  const float* m1b  = (const float*)d_in[13];
  const float* aw0  = (const float*)d_in[14];
  const float* ab0  = (const float*)d_in[15];
  const float* aw1  = (const float*)d_in[16];
  const float* ab1  = (const float*)d_in[17];

  // workspace layout — total ~59.1 MB
  char* ws = (char*)d_ws;
  __bf16* buf0  = (__bf16*)(ws + 0LL);            // 32 MB: preC, later a1C (disjoint lifetimes per chunk)
  __bf16* xnbfC = (__bf16*)(ws + 33554432LL);     // 8 MB
  __bf16* ymidbC= (__bf16*)(ws + 41943040LL);     // 8 MB
  __bf16* wihb  = (__bf16*)(ws + 50331648LL);     // 2 MB
  __bf16* whhb  = (__bf16*)(ws + 52428800LL);     // 2 MB
  __bf16* m0bf  = (__bf16*)(ws + 54525952LL);     // 2 MB
  __bf16* m1bf  = (__bf16*)(ws + 56623104LL);     // 2 MB
  __bf16* awT0  = (__bf16*)(ws + 58720256LL);     // 64 KB
  __bf16* awT1  = (__bf16*)(ws + 58785792LL);     // 64 KB
  unsigned long long* HP = (unsigned long long*)(ws + 58851328LL);  // 128 KB packet buffers
  float*  cstate= (float*) (ws + 58982400LL);     // 64 KB
  unsigned int* mode = (unsigned int*)(ws + 59047936LL);
  __bf16* preC = buf0;
  __bf16* a1C  = buf0;

  float* out  = (float*)d_out;
  float* hout = out + (size_t)TB_ * D_;
  float* cout = hout + B_ * D_;

  // zero packet tags: kills cross-replay stale-tag aliasing
  hipMemsetAsync(HP, 0, 131072, stream);
  detect_first_kernel<<<1, 256, 0, stream>>>((const unsigned char*)first, mode);
  convert_w_kernel<<<4352, 256, 0, stream>>>(Wih, Whh, m0w, m1w, aw0, aw1,
                                             wihb, whhb, m0bf, m1bf, awT0, awT1);
  for (int c = 0; c < 4; ++c) {
    const size_t ro = (size_t)c * RCH_;
    ln_kernel<<<RCH_/4, 256, 0, stream>>>(x + ro * D_, ln_g, ln_b, xnbfC);
    gemm_bt<0,1,1><<<dim3(RCH_/128, FF_/128), 256, 0, stream>>>(xnbfC, wihb, bih, bhh,
                                                                nullptr, preC, RCH_, 2048, 512);
    lstm_scan<<<16, 512, 0, stream>>>(whhb, preC, x, first, h0, c0, cstate, ymidbC,
                                      HP, mode, hout, cout, c * TCH_);
    gemm_bt<1,1,0><<<dim3(RCH_/128, FF_/128), 256, 0, stream>>>(ymidbC, m0bf, m0b, nullptr,
                                                                nullptr, a1C, RCH_, FF_, 512);
    gemm_bt<0,0,0><<<dim3(RCH_/128, D_/128), 256, 0, stream>>>(a1C, m1bf, m1b, nullptr,
                                                               out + ro * D_, nullptr, RCH_, D_, FF_);
    adapter_out_kernel<<<RCH_/16, 256, 0, stream>>>(out + ro * D_, ymidbC, awT0, awT1, ab0, ab1);
  }
}